// Round 4
// baseline (117.237 us; speedup 1.0000x reference)
//
#include <hip/hip_runtime.h>

// SDT forward, fp16 MFMA (fp32 accumulate), v5: SINGLE compute kernel.
// No workspace, no pre-pass: B-fragments are gathered directly from fp32 Ws
// (522 KB, L2-resident per XCD) with in-register f32->f16 convert, pipelined
// 6 chunks deep. value (65 KB) likewise gathered as raw floats before phase
// 2b and converted in 2c. reg slot zeroed by a 4-byte memset node.
// Numerically identical to v4 (same fp16 rounding points); absmax ~2.4e-4.
// Lessons kept: no cooperative grid.sync (v3: ~40+ us); deep prefetch (v4);
// register-fused sigmoid/bias/reg epilogue (v3/v4).
// Layouts (HW-verified): A/B^T lane&15->row(n), (lane>>4)*8->k;
// C/D: col=lane&15, row=(lane>>4)*4+reg.

typedef __attribute__((ext_vector_type(8))) _Float16 half8;
typedef __attribute__((ext_vector_type(4))) _Float16 half4;
typedef __attribute__((ext_vector_type(4))) float floatx4;

constexpr int O = 64;
constexpr int XSTR = 520;   // x-tile LDS row stride (halfs): 1040 B
constexpr int PSTR = 280;   // P_h row stride (halfs): 560 B (16B-aligned)
constexpr int LSTR = 260;   // L_s row stride (floats)

__global__ __launch_bounds__(512, 1) void sdt_main(
    const float* __restrict__ x, const float* __restrict__ Ws,
    const float* __restrict__ value, const float* __restrict__ bs,
    float* __restrict__ out, float* __restrict__ reg_out)
{
  // Overlay: phase 1 x-tile fp16 (33280 B) / phase 2 L_s + P_h.
  __shared__ __align__(16) char smem[33280 + 17920];
  _Float16* xh_s = (_Float16*)smem;              // [32][520]
  float*    L_s  = (float*)smem;                 // [32][260]
  _Float16* P_h  = (_Float16*)(smem + 33280);    // [32][280]
  __shared__ float red_s[8];

  const int t = threadIdx.x, lane = t & 63, w = t >> 6;   // 8 waves
  const int q = lane >> 4, r16 = lane & 15;
  const int R0 = blockIdx.x * 32;

  // Per-lane W gather bases: wave w owns n-tiles 2w (cols w*32+r16) and
  // 2w+1 (cols w*32+16+r16). col0 <= 239 always valid; col1 == 255 only for
  // (w==7, r16==15) -> zero-pad that lane's second fragment.
  const int col0 = w * 32 + r16, col1 = col0 + 16;
  const bool v1 = (col1 < 255);
  const float* pW0 = Ws + col0;
  const float* pW1 = Ws + col1;

  // raw[s][0..7] = tile0 elems, raw[s][8..15] = tile1 elems for one chunk.
  float raw[6][16];

  // ---- issue x loads first (HBM-cold, longest latency) ----
  const int xrowi = t >> 4, xl4 = (t & 15) * 4;
  const float* xrow = x + (size_t)(R0 + xrowi) * 512;
  float4 xv[8];
#pragma unroll
  for (int i = 0; i < 8; ++i) xv[i] = *(const float4*)(xrow + xl4 + i * 64);

  // ---- issue W gathers for chunks 0..5 (pipeline fill) ----
#pragma unroll
  for (int s = 0; s < 6; ++s) {
    const int kb = s * 32 + q * 8;
#pragma unroll
    for (int j = 0; j < 8; ++j) {
      raw[s][j]     = pW0[(size_t)(kb + j) * 255];
      raw[s][8 + j] = v1 ? pW1[(size_t)(kb + j) * 255] : 0.f;
    }
  }

  // ---- convert + store x tile to LDS ----
#pragma unroll
  for (int i = 0; i < 8; ++i) {
    half4 h = {(_Float16)xv[i].x, (_Float16)xv[i].y,
               (_Float16)xv[i].z, (_Float16)xv[i].w};
    *(half4*)&xh_s[xrowi * XSTR + xl4 + i * 64] = h;
  }
  __syncthreads();   // barrier 1: x tile staged

  // ---- K-loop: 16 chunks of K=32, 4 MFMA each, gather depth 6 ----
  floatx4 acc00 = {0,0,0,0}, acc01 = {0,0,0,0}, acc10 = {0,0,0,0}, acc11 = {0,0,0,0};
  const int a0off = r16 * XSTR + q * 8, a1off = (16 + r16) * XSTR + q * 8;

#pragma unroll
  for (int c = 0; c < 16; ++c) {
    const int s = c % 6;
    _Float16 b0e[8], b1e[8];
#pragma unroll
    for (int j = 0; j < 8; ++j) {
      b0e[j] = (_Float16)raw[s][j];
      b1e[j] = (_Float16)raw[s][8 + j];
    }
    half8 b0 = *(half8*)b0e, b1 = *(half8*)b1e;
    if (c < 10) {                      // refill slot with chunk c+6
      const int kb = (c + 6) * 32 + q * 8;
#pragma unroll
      for (int j = 0; j < 8; ++j) {
        raw[s][j]     = pW0[(size_t)(kb + j) * 255];
        raw[s][8 + j] = v1 ? pW1[(size_t)(kb + j) * 255] : 0.f;
      }
    }
    half8 a0 = *(const half8*)&xh_s[a0off + c * 32];
    half8 a1 = *(const half8*)&xh_s[a1off + c * 32];
    acc00 = __builtin_amdgcn_mfma_f32_16x16x32_f16(a0, b0, acc00, 0, 0, 0);
    acc01 = __builtin_amdgcn_mfma_f32_16x16x32_f16(a0, b1, acc01, 0, 0, 0);
    acc10 = __builtin_amdgcn_mfma_f32_16x16x32_f16(a1, b0, acc10, 0, 0, 0);
    acc11 = __builtin_amdgcn_mfma_f32_16x16x32_f16(a1, b1, acc11, 0, 0, 0);
  }

  // ---- fused epilogue: bias + sigmoid + reg on registers (pre-barrier) ----
  const int c0 = col0, c1 = col1;      // c0 <= 239; c1 <= 255
  float pv00[4], pv01[4], pv10[4], pv11[4];
  float s0 = 0.f, s1 = 0.f;
  {
    const float b0 = bs[c0];
    const float b1 = v1 ? bs[c1] : 0.f;
#pragma unroll
    for (int r = 0; r < 4; ++r) {
      float p;
      p = 1.f / (1.f + __expf(-(acc00[r] + b0))); pv00[r] = p;
      s0 += __logf(fmaxf(p * (1.f - p), 1e-5f));
      p = 1.f / (1.f + __expf(-(acc10[r] + b0))); pv10[r] = p;
      s0 += __logf(fmaxf(p * (1.f - p), 1e-5f));
      p = 1.f / (1.f + __expf(-(acc01[r] + b1))); pv01[r] = p;
      s1 += __logf(fmaxf(p * (1.f - p), 1e-5f));
      p = 1.f / (1.f + __expf(-(acc11[r] + b1))); pv11[r] = p;
      s1 += __logf(fmaxf(p * (1.f - p), 1e-5f));
    }
  }
  float rsum;
  {
    const int d0 = 31 - __clz(c0 + 1);
    rsum = s0 * (-0.5f / (8192.0f * (float)(1 << d0)));
    if (v1) {
      const int d1 = 31 - __clz(c1 + 1);
      rsum += s1 * (-0.5f / (8192.0f * (float)(1 << d1)));
    }
  }
#pragma unroll
  for (int off = 32; off; off >>= 1) rsum += __shfl_down(rsum, off, 64);

  __syncthreads();   // barrier 2: all xh_s reads done before L_s overlays it

  {
#pragma unroll
    for (int r = 0; r < 4; ++r) {
      const int row0 = q * 4 + r, row1 = row0 + 16;
      L_s[row0 * LSTR + c0] = pv00[r];
      L_s[row0 * LSTR + c1] = pv01[r];   // col 255 in-bounds, never read
      L_s[row1 * LSTR + c0] = pv10[r];
      L_s[row1 * LSTR + c1] = pv11[r];
    }
    if (lane == 0) red_s[w] = rsum;
  }
  __syncthreads();   // barrier 3: probabilities visible to all waves

  if (t == 0) {
    float s = 0.f;
#pragma unroll
    for (int i = 0; i < 8; ++i) s += red_s[i];
    atomicAdd(reg_out, s);
  }

  // ---- issue value gathers (raw fp32; latency hides under phase 2b) ----
  const int tm = w & 1, tn = w >> 1;       // 2 m-tiles x 4 n-tiles of 16
  float rawV[64];
  {
    const float* pV = value + tn * 16 + r16;
#pragma unroll
    for (int kc = 0; kc < 8; ++kc)
#pragma unroll
      for (int j = 0; j < 8; ++j)
        rawV[kc * 8 + j] = pV[(size_t)(kc * 32 + q * 8 + j) * 64];
  }

  // ---- phase 2b: path products, 8 leaves x 2 rows per thread ----
  {
    const int g8 = t & 31, rp = t >> 5;
    const int Lb = g8 * 8;
#pragma unroll
    for (int rr = 0; rr < 2; ++rr) {
      const int row = rp * 2 + rr;
      const float* Lr = &L_s[row * LSTR];
      float pre = 1.f;
#pragma unroll
      for (int dd = 0; dd < 5; ++dd) {
        float p = Lr[(1 << dd) - 1 + (Lb >> (8 - dd))];
        float br = ((Lb >> (7 - dd)) & 1) ? (1.f - p) : p;
        pre *= fmaxf(br, 1e-5f);
      }
      float p5 = Lr[31 + g8];
      float s5a = fmaxf(p5, 1e-5f), s5b = fmaxf(1.f - p5, 1e-5f);
      float p6a = Lr[63 + 2 * g8], p6b = Lr[63 + 2 * g8 + 1];
      float p7v[4];
#pragma unroll
      for (int m = 0; m < 4; ++m) p7v[m] = Lr[127 + 4 * g8 + m];
      _Float16 ph[8];
#pragma unroll
      for (int j = 0; j < 8; ++j) {
        float s5 = (j & 4) ? s5b : s5a;
        float p6 = (j & 4) ? p6b : p6a;
        float s6 = fmaxf((j & 2) ? (1.f - p6) : p6, 1e-5f);
        float p7 = p7v[j >> 1];
        float s7 = fmaxf((j & 1) ? (1.f - p7) : p7, 1e-5f);
        ph[j] = (_Float16)(pre * s5 * s6 * s7);
      }
      *(half8*)&P_h[row * PSTR + Lb] = *(half8*)ph;
    }
  }
  __syncthreads();   // barrier 4: P_h ready

  // ---- phase 2c: out[32][64] = P @ value via fp16 MFMA ----
  {
    floatx4 C = {0, 0, 0, 0};
    const _Float16* pa = &P_h[(tm * 16 + r16) * PSTR + q * 8];
#pragma unroll
    for (int kc = 0; kc < 8; ++kc) {
      _Float16 be[8];
#pragma unroll
      for (int j = 0; j < 8; ++j) be[j] = (_Float16)rawV[kc * 8 + j];
      half8 B8 = *(half8*)be;
      half8 A8 = *(const half8*)(pa + kc * 32);
      C = __builtin_amdgcn_mfma_f32_16x16x32_f16(A8, B8, C, 0, 0, 0);
    }
    const int col = tn * 16 + r16;
#pragma unroll
    for (int r = 0; r < 4; ++r) {
      int row = tm * 16 + q * 4 + r;
      out[(size_t)(R0 + row) * O + col] = C[r];
    }
  }
}

extern "C" void kernel_launch(void* const* d_in, const int* in_sizes, int n_in,
                              void* d_out, int out_size, void* d_ws, size_t ws_size,
                              hipStream_t stream) {
  const float* x     = (const float*)d_in[0];
  const float* Ws    = (const float*)d_in[1];
  const float* bs    = (const float*)d_in[2];
  const float* value = (const float*)d_in[3];
  float* outp = (float*)d_out;
  float* reg_slot = outp + (size_t)8192 * O;          // index 524288

  hipMemsetAsync(reg_slot, 0, 4, stream);             // zero reg accumulator
  sdt_main<<<256, 512, 0, stream>>>(x, Ws, value, bs, outp, reg_slot);
}

// Round 5
// 83.571 us; speedup vs baseline: 1.4028x; 1.4028x over previous
//
#include <hip/hip_runtime.h>

// SDT forward, fp16 MFMA (fp32 accumulate), v6: v4 skeleton at 16 waves/block.
//   256 blocks x 1024 threads (4 waves/SIMD, 2x v4) -- same per-block wt/LDS
//   traffic as v4, double latency hiding. Wave w: m-tile (w>>3), n-tiles
//   2*(w&7), 2*(w&7)+1. B preload 8 chunks pre-barrier + 8-ahead refill.
// Lessons: no coop grid.sync (v3, +40us); no fp32 scalar gather (v5, +35us:
//   320 scalar loads/thread + vmcnt>63 kills pipelining); frag-major fp16 wt
//   half8 loads are the right B path (v1/v4).
// Layouts (HW-verified): A/B^T lane&15->row(n), (lane>>4)*8->k;
// C/D: col=lane&15, row=(lane>>4)*4+reg.

typedef __attribute__((ext_vector_type(8))) _Float16 half8;
typedef __attribute__((ext_vector_type(4))) _Float16 half4;
typedef __attribute__((ext_vector_type(4))) float floatx4;

constexpr int O = 64;
constexpr int XSTR = 520;   // x-tile LDS row stride (halfs): 1040 B
constexpr int PSTR = 280;   // P_h row stride (halfs): 560 B (16B-aligned)
constexpr int LSTR = 260;   // L_s row stride (floats)

// ---- pre: W^T fp16 frag-major; value^T fp16 frag-major; zero reg ----
// wt layout: block (T*16+c) of 1024 B; lane=(q*16+r16); elem j:
//   wt[(T*16+c)*512 + lane*8 + j] = W[k= c*32+q*8+j][n= T*16+r16]
__global__ __launch_bounds__(256) void sdt_pre(
    const float* __restrict__ Ws, const float* __restrict__ value,
    _Float16* __restrict__ wt, _Float16* __restrict__ vt,
    float* __restrict__ reg_slot)
{
  const int bid = blockIdx.x, t = threadIdx.x;
  if (bid < 64) {                      // W: 8 k-rows per block, coalesced reads
    const int k0 = bid * 8;
    const int n = t;                   // 0..255
    const int T = n >> 4, r = n & 15;
    const int c = k0 >> 5, q = (k0 >> 3) & 3;
    _Float16 v8[8];
#pragma unroll
    for (int kk = 0; kk < 8; ++kk) {
      float f = (n < 255) ? Ws[(size_t)(k0 + kk) * 255 + n] : 0.f;
      v8[kk] = (_Float16)f;
    }
    *(half8*)&wt[(size_t)(T * 16 + c) * 512 + (q * 16 + r) * 8] = *(half8*)v8;
  } else {                             // value^T: 64 k-rows per block
    const int k0 = (bid - 64) * 64;
#pragma unroll
    for (int j = 0; j < 16; ++j) {
      int e = t + j * 256;             // 0..4095
      int k = k0 + (e >> 6), n = e & 63;
      float f = value[(size_t)k * O + n];
      int T = n >> 4, r = n & 15, kc = k >> 5, q = (k >> 3) & 3, jj = k & 7;
      vt[(size_t)(T * 8 + kc) * 512 + (q * 16 + r) * 8 + jj] = (_Float16)f;
    }
    if (bid == 64 && t == 0) *reg_slot = 0.f;
  }
}

__global__ __launch_bounds__(1024, 1) void sdt_main(
    const float* __restrict__ x, const _Float16* __restrict__ wt,
    const _Float16* __restrict__ vt, const float* __restrict__ bs,
    float* __restrict__ out, float* __restrict__ reg_out)
{
  // Overlay: phase 1 x-tile fp16 (33280 B) / phase 2 L_s + P_h.
  __shared__ __align__(16) char smem[33280 + 17920];
  _Float16* xh_s = (_Float16*)smem;              // [32][520]
  float*    L_s  = (float*)smem;                 // [32][260]
  _Float16* P_h  = (_Float16*)(smem + 33280);    // [32][280]
  __shared__ float red_s[16];

  const int t = threadIdx.x, lane = t & 63, w = t >> 6;   // 16 waves
  const int q = lane >> 4, r16 = lane & 15;
  const int R0 = blockIdx.x * 32;
  const int w_m = w >> 3, w_n = w & 7;

  // ---- issue x loads first (HBM-cold, longest latency): 4 float4/thread ----
  const int xrow_i = t >> 5, xcid = t & 31;
  const float* xrow = x + (size_t)(R0 + xrow_i) * 512;
  float4 xv[4];
#pragma unroll
  for (int i = 0; i < 4; ++i)
    xv[i] = *(const float4*)(xrow + xcid * 4 + i * 128);

  // ---- B preload: chunks 0..7 for both n-tiles (64 VGPRs) ----
  const _Float16* pb0 = wt + (size_t)(2 * w_n) * 16 * 512 + lane * 8;
  const _Float16* pb1 = wt + (size_t)(2 * w_n + 1) * 16 * 512 + lane * 8;
  half8 Bv0[8], Bv1[8];
#pragma unroll
  for (int c = 0; c < 8; ++c) {
    Bv0[c] = *(const half8*)(pb0 + c * 512);
    Bv1[c] = *(const half8*)(pb1 + c * 512);
  }

  // ---- convert + store x tile to LDS ----
#pragma unroll
  for (int i = 0; i < 4; ++i) {
    half4 h = {(_Float16)xv[i].x, (_Float16)xv[i].y,
               (_Float16)xv[i].z, (_Float16)xv[i].w};
    *(half4*)&xh_s[xrow_i * XSTR + xcid * 4 + i * 128] = h;
  }
  __syncthreads();   // barrier 1: x tile staged

  // ---- K-loop: 16 chunks of K=32, 1 A-read + 2 MFMA each, refill 8-ahead ----
  floatx4 acc0 = {0,0,0,0}, acc1 = {0,0,0,0};
  const int aoff = (w_m * 16 + r16) * XSTR + q * 8;

#pragma unroll
  for (int c = 0; c < 16; ++c) {
    half8 b0 = Bv0[c & 7], b1 = Bv1[c & 7];
    if (c < 8) {                       // refill slot with chunk c+8
      Bv0[c & 7] = *(const half8*)(pb0 + (c + 8) * 512);
      Bv1[c & 7] = *(const half8*)(pb1 + (c + 8) * 512);
    }
    half8 a = *(const half8*)&xh_s[aoff + c * 32];
    acc0 = __builtin_amdgcn_mfma_f32_16x16x32_f16(a, b0, acc0, 0, 0, 0);
    acc1 = __builtin_amdgcn_mfma_f32_16x16x32_f16(a, b1, acc1, 0, 0, 0);
  }

  // ---- fused epilogue: bias + sigmoid + reg on registers (pre-barrier) ----
  const int c0 = w_n * 32 + r16, c1 = c0 + 16;   // c0 <= 239; c1 <= 255
  const bool v1ok = (c1 < 255);
  float pv0[4], pv1[4];
  float s0 = 0.f, s1 = 0.f;
  {
    const float b0 = bs[c0];
    const float b1 = v1ok ? bs[c1] : 0.f;
#pragma unroll
    for (int r = 0; r < 4; ++r) {
      float p;
      p = 1.f / (1.f + __expf(-(acc0[r] + b0))); pv0[r] = p;
      s0 += __logf(fmaxf(p * (1.f - p), 1e-5f));
      p = 1.f / (1.f + __expf(-(acc1[r] + b1))); pv1[r] = p;
      s1 += __logf(fmaxf(p * (1.f - p), 1e-5f));
    }
  }
  float rsum;
  {
    const int d0 = 31 - __clz(c0 + 1);
    rsum = s0 * (-0.5f / (8192.0f * (float)(1 << d0)));
    if (v1ok) {
      const int d1 = 31 - __clz(c1 + 1);
      rsum += s1 * (-0.5f / (8192.0f * (float)(1 << d1)));
    }
  }
#pragma unroll
  for (int off = 32; off; off >>= 1) rsum += __shfl_down(rsum, off, 64);

  __syncthreads();   // barrier 2: all xh_s reads done before L_s overlays it

  {
#pragma unroll
    for (int r = 0; r < 4; ++r) {
      const int row = w_m * 16 + q * 4 + r;
      L_s[row * LSTR + c0] = pv0[r];
      L_s[row * LSTR + c1] = pv1[r];   // col 255 in-bounds, never read
    }
    if (lane == 0) red_s[w] = rsum;
  }
  __syncthreads();   // barrier 3: probabilities visible to all waves

  if (t == 0) {
    float s = 0.f;
#pragma unroll
    for (int i = 0; i < 16; ++i) s += red_s[i];
    atomicAdd(reg_out, s);
  }

  // ---- prefetch vt B-frags for phase 2c (waves 0-7; hides under 2b) ----
  half8 VB[8];
  if (w < 8) {
    const int tn = w >> 1;
    const _Float16* vb = vt + (size_t)(tn * 8) * 512 + lane * 8;
#pragma unroll
    for (int kc = 0; kc < 8; ++kc) VB[kc] = *(const half8*)(vb + kc * 512);
  }

  // ---- phase 2b: path products, 8 leaves x 1 row per thread ----
  {
    const int g8 = t & 31, row = t >> 5;         // row 0..31
    const int Lb = g8 * 8;
    const float* Lr = &L_s[row * LSTR];
    float pre = 1.f;
#pragma unroll
    for (int dd = 0; dd < 5; ++dd) {
      float p = Lr[(1 << dd) - 1 + (Lb >> (8 - dd))];
      float br = ((Lb >> (7 - dd)) & 1) ? (1.f - p) : p;
      pre *= fmaxf(br, 1e-5f);
    }
    float p5 = Lr[31 + g8];
    float s5a = fmaxf(p5, 1e-5f), s5b = fmaxf(1.f - p5, 1e-5f);
    float p6a = Lr[63 + 2 * g8], p6b = Lr[63 + 2 * g8 + 1];
    float p7v[4];
#pragma unroll
    for (int m = 0; m < 4; ++m) p7v[m] = Lr[127 + 4 * g8 + m];
    _Float16 ph[8];
#pragma unroll
    for (int j = 0; j < 8; ++j) {
      float s5 = (j & 4) ? s5b : s5a;
      float p6 = (j & 4) ? p6b : p6a;
      float s6 = fmaxf((j & 2) ? (1.f - p6) : p6, 1e-5f);
      float p7 = p7v[j >> 1];
      float s7 = fmaxf((j & 1) ? (1.f - p7) : p7, 1e-5f);
      ph[j] = (_Float16)(pre * s5 * s6 * s7);
    }
    *(half8*)&P_h[row * PSTR + Lb] = *(half8*)ph;
  }
  __syncthreads();   // barrier 4: P_h ready

  // ---- phase 2c: out[32][64] = P @ value via fp16 MFMA (waves 0-7) ----
  if (w < 8) {
    const int tm = w & 1, tn = w >> 1;       // 2 m-tiles x 4 n-tiles of 16
    floatx4 C = {0, 0, 0, 0};
    const _Float16* pa = &P_h[(tm * 16 + r16) * PSTR + q * 8];
#pragma unroll
    for (int kc = 0; kc < 8; ++kc) {
      half8 A8 = *(const half8*)(pa + kc * 32);
      C = __builtin_amdgcn_mfma_f32_16x16x32_f16(A8, VB[kc], C, 0, 0, 0);
    }
    const int col = tn * 16 + r16;
#pragma unroll
    for (int r = 0; r < 4; ++r) {
      int row = tm * 16 + q * 4 + r;
      out[(size_t)(R0 + row) * O + col] = C[r];
    }
  }
}

extern "C" void kernel_launch(void* const* d_in, const int* in_sizes, int n_in,
                              void* d_out, int out_size, void* d_ws, size_t ws_size,
                              hipStream_t stream) {
  const float* x     = (const float*)d_in[0];
  const float* Ws    = (const float*)d_in[1];
  const float* bs    = (const float*)d_in[2];
  const float* value = (const float*)d_in[3];
  float* outp = (float*)d_out;
  float* reg_slot = outp + (size_t)8192 * O;          // index 524288
  _Float16* wt = (_Float16*)d_ws;                     // frag-major W^T fp16, 256 KB
  _Float16* vt = wt + 256 * 512;                      // frag-major value^T fp16, 32 KB

  sdt_pre<<<68, 256, 0, stream>>>(Ws, value, wt, vt, reg_slot);
  sdt_main<<<256, 1024, 0, stream>>>(x, wt, vt, bs, outp, reg_slot);
}

// Round 6
// 81.906 us; speedup vs baseline: 1.4314x; 1.0203x over previous
//
#include <hip/hip_runtime.h>

// SDT forward, fp16 MFMA (fp32 accumulate), v7: v4 dataflow, serialization
// stripped: (1) no LDS overlay -> barrier count 4->3; (2) ALL 16 B-chunks
// preloaded pre-barrier (no in-loop VMEM); (3) 512-thread pre (2x parallel).
// Lessons: coop grid.sync +40us (v3); fp32 scalar gather +35us = L2-gather-BW
// bound (v5); extra waves/SIMD = no effect (v6) -> not TLP-hideable latency.
// Layouts (HW-verified): A/B^T lane&15->row(n), (lane>>4)*8->k;
// C/D: col=lane&15, row=(lane>>4)*4+reg.

typedef __attribute__((ext_vector_type(8))) _Float16 half8;
typedef __attribute__((ext_vector_type(4))) _Float16 half4;
typedef __attribute__((ext_vector_type(4))) float floatx4;

constexpr int O = 64;
constexpr int XSTR = 520;   // x-tile LDS row stride (halfs): 1040 B
constexpr int PSTR = 280;   // P_h row stride (halfs): 560 B (16B-aligned)
constexpr int LSTR = 260;   // L_s row stride (floats)

// ---- pre: W^T fp16 frag-major; value^T fp16 frag-major; zero reg ----
// wt layout: block (T*16+c) of 1024 B; lane=(q*16+r16); elem j:
//   wt[(T*16+c)*512 + lane*8 + j] = W[k= c*32+q*8+j][n= T*16+r16]
__global__ __launch_bounds__(512) void sdt_pre(
    const float* __restrict__ Ws, const float* __restrict__ value,
    _Float16* __restrict__ wt, _Float16* __restrict__ vt,
    float* __restrict__ reg_slot)
{
  const int bid = blockIdx.x, t = threadIdx.x;
  if (bid < 64) {                      // W: 8 k-rows per block, coalesced reads
    const int k0 = bid * 8;
    const int n = t & 255, hf = t >> 8;            // hf: which 4 of the 8 kk
    const int T = n >> 4, r = n & 15;
    const int c = k0 >> 5, q = (k0 >> 3) & 3;      // k0..k0+7 share (c,q)
    _Float16 v4h[4];
#pragma unroll
    for (int i = 0; i < 4; ++i) {
      const int kk = hf * 4 + i;
      float f = (n < 255) ? Ws[(size_t)(k0 + kk) * 255 + n] : 0.f;
      v4h[i] = (_Float16)f;
    }
    *(half4*)&wt[(size_t)(T * 16 + c) * 512 + (q * 16 + r) * 8 + hf * 4] =
        *(half4*)v4h;
  } else {                             // value^T: 64 k-rows per block
    const int k0 = (bid - 64) * 64;
#pragma unroll
    for (int j = 0; j < 8; ++j) {
      int e = t + j * 512;             // 0..4095
      int k = k0 + (e >> 6), n = e & 63;
      float f = value[(size_t)k * O + n];
      int T = n >> 4, r = n & 15, kc = k >> 5, q = (k >> 3) & 3, jj = k & 7;
      vt[(size_t)(T * 8 + kc) * 512 + (q * 16 + r) * 8 + jj] = (_Float16)f;
    }
    if (bid == 64 && t == 0) *reg_slot = 0.f;
  }
}

__global__ __launch_bounds__(512, 1) void sdt_main(
    const float* __restrict__ x, const _Float16* __restrict__ wt,
    const _Float16* __restrict__ vt, const float* __restrict__ bs,
    float* __restrict__ out, float* __restrict__ reg_out)
{
  // Disjoint LDS (no overlay): xh 33280 + L_s 33280 + P_h 17920 = 84480 B.
  __shared__ __align__(16) char smem[33280 + 33280 + 17920];
  _Float16* xh_s = (_Float16*)smem;               // [32][520]
  float*    L_s  = (float*)(smem + 33280);        // [32][260]
  _Float16* P_h  = (_Float16*)(smem + 66560);     // [32][280]
  __shared__ float red_s[8];

  const int t = threadIdx.x, lane = t & 63, w = t >> 6;   // 8 waves
  const int q = lane >> 4, r16 = lane & 15;
  const int R0 = blockIdx.x * 32;

  // ---- issue x loads first (HBM, longest latency; oldest -> drain first) ----
  const int xrowi = t >> 4, xl4 = (t & 15) * 4;
  const float* xrow = x + (size_t)(R0 + xrowi) * 512;
  float4 xv[8];
#pragma unroll
  for (int i = 0; i < 8; ++i) xv[i] = *(const float4*)(xrow + xl4 + i * 64);

  // ---- preload ALL 16 B-chunks for both n-tiles (128 VGPRs) ----
  const _Float16* pb0 = wt + (size_t)(2 * w) * 16 * 512 + lane * 8;
  const _Float16* pb1 = wt + (size_t)(2 * w + 1) * 16 * 512 + lane * 8;
  half8 B0[16], B1[16];
#pragma unroll
  for (int c = 0; c < 16; ++c) {
    B0[c] = *(const half8*)(pb0 + c * 512);
    B1[c] = *(const half8*)(pb1 + c * 512);
  }

  // ---- convert + store x tile to LDS ----
#pragma unroll
  for (int i = 0; i < 8; ++i) {
    half4 h = {(_Float16)xv[i].x, (_Float16)xv[i].y,
               (_Float16)xv[i].z, (_Float16)xv[i].w};
    *(half4*)&xh_s[xrowi * XSTR + xl4 + i * 64] = h;
  }
  __syncthreads();   // barrier 1: x tile staged

  // ---- K-loop: 16 chunks of K=32, pure LDS + MFMA (no VMEM) ----
  floatx4 acc00 = {0,0,0,0}, acc01 = {0,0,0,0}, acc10 = {0,0,0,0}, acc11 = {0,0,0,0};
  const int a0off = r16 * XSTR + q * 8, a1off = (16 + r16) * XSTR + q * 8;

#pragma unroll
  for (int c = 0; c < 16; ++c) {
    half8 a0 = *(const half8*)&xh_s[a0off + c * 32];
    half8 a1 = *(const half8*)&xh_s[a1off + c * 32];
    acc00 = __builtin_amdgcn_mfma_f32_16x16x32_f16(a0, B0[c], acc00, 0, 0, 0);
    acc01 = __builtin_amdgcn_mfma_f32_16x16x32_f16(a0, B1[c], acc01, 0, 0, 0);
    acc10 = __builtin_amdgcn_mfma_f32_16x16x32_f16(a1, B0[c], acc10, 0, 0, 0);
    acc11 = __builtin_amdgcn_mfma_f32_16x16x32_f16(a1, B1[c], acc11, 0, 0, 0);
  }

  // ---- fused epilogue: bias + sigmoid + reg on registers ----
  const int c0 = w * 32 + r16, c1 = c0 + 16;   // c0 <= 239; c1 <= 255
  const bool v1ok = (c1 < 255);
  float pv00[4], pv01[4], pv10[4], pv11[4];
  float s0 = 0.f, s1 = 0.f;
  {
    const float b0 = bs[c0];
    const float b1 = v1ok ? bs[c1] : 0.f;
#pragma unroll
    for (int r = 0; r < 4; ++r) {
      float p;
      p = 1.f / (1.f + __expf(-(acc00[r] + b0))); pv00[r] = p;
      s0 += __logf(fmaxf(p * (1.f - p), 1e-5f));
      p = 1.f / (1.f + __expf(-(acc10[r] + b0))); pv10[r] = p;
      s0 += __logf(fmaxf(p * (1.f - p), 1e-5f));
      p = 1.f / (1.f + __expf(-(acc01[r] + b1))); pv01[r] = p;
      s1 += __logf(fmaxf(p * (1.f - p), 1e-5f));
      p = 1.f / (1.f + __expf(-(acc11[r] + b1))); pv11[r] = p;
      s1 += __logf(fmaxf(p * (1.f - p), 1e-5f));
    }
  }
  float rsum;
  {
    const int d0 = 31 - __clz(c0 + 1);
    rsum = s0 * (-0.5f / (8192.0f * (float)(1 << d0)));
    if (v1ok) {
      const int d1 = 31 - __clz(c1 + 1);
      rsum += s1 * (-0.5f / (8192.0f * (float)(1 << d1)));
    }
  }
#pragma unroll
  for (int off = 32; off; off >>= 1) rsum += __shfl_down(rsum, off, 64);

  // ---- write probabilities to L_s (disjoint from xh_s: no WAR barrier) ----
  {
#pragma unroll
    for (int r = 0; r < 4; ++r) {
      const int row0 = q * 4 + r, row1 = row0 + 16;
      L_s[row0 * LSTR + c0] = pv00[r];
      L_s[row0 * LSTR + c1] = pv01[r];   // col 255 in-bounds, never read
      L_s[row1 * LSTR + c0] = pv10[r];
      L_s[row1 * LSTR + c1] = pv11[r];
    }
    if (lane == 0) red_s[w] = rsum;
  }
  __syncthreads();   // barrier 2: L_s + red_s visible

  if (t == 0) {
    float s = 0.f;
#pragma unroll
    for (int i = 0; i < 8; ++i) s += red_s[i];
    atomicAdd(reg_out, s);
  }

  // ---- prefetch vt B-frags for phase 2c (latency hides under 2b) ----
  half8 VB[8];
  {
    const int tn = w >> 1;
    const _Float16* vb = vt + (size_t)(tn * 8) * 512 + lane * 8;
#pragma unroll
    for (int kc = 0; kc < 8; ++kc) VB[kc] = *(const half8*)(vb + kc * 512);
  }

  // ---- phase 2b: path products, 8 leaves x 2 rows per thread ----
  {
    const int g8 = t & 31, rp = t >> 5;
    const int Lb = g8 * 8;
#pragma unroll
    for (int rr = 0; rr < 2; ++rr) {
      const int row = rp * 2 + rr;
      const float* Lr = &L_s[row * LSTR];
      float pre = 1.f;
#pragma unroll
      for (int dd = 0; dd < 5; ++dd) {
        float p = Lr[(1 << dd) - 1 + (Lb >> (8 - dd))];
        float br = ((Lb >> (7 - dd)) & 1) ? (1.f - p) : p;
        pre *= fmaxf(br, 1e-5f);
      }
      float p5 = Lr[31 + g8];
      float s5a = fmaxf(p5, 1e-5f), s5b = fmaxf(1.f - p5, 1e-5f);
      float p6a = Lr[63 + 2 * g8], p6b = Lr[63 + 2 * g8 + 1];
      float p7v[4];
#pragma unroll
      for (int m = 0; m < 4; ++m) p7v[m] = Lr[127 + 4 * g8 + m];
      _Float16 ph[8];
#pragma unroll
      for (int j = 0; j < 8; ++j) {
        float s5 = (j & 4) ? s5b : s5a;
        float p6 = (j & 4) ? p6b : p6a;
        float s6 = fmaxf((j & 2) ? (1.f - p6) : p6, 1e-5f);
        float p7 = p7v[j >> 1];
        float s7 = fmaxf((j & 1) ? (1.f - p7) : p7, 1e-5f);
        ph[j] = (_Float16)(pre * s5 * s6 * s7);
      }
      *(half8*)&P_h[row * PSTR + Lb] = *(half8*)ph;
    }
  }
  __syncthreads();   // barrier 3: P_h ready

  // ---- phase 2c: out[32][64] = P @ value via fp16 MFMA ----
  {
    const int tm = w & 1, tn = w >> 1;       // 2 m-tiles x 4 n-tiles of 16
    floatx4 C = {0, 0, 0, 0};
    const _Float16* pa = &P_h[(tm * 16 + r16) * PSTR + q * 8];
#pragma unroll
    for (int kc = 0; kc < 8; ++kc) {
      half8 A8 = *(const half8*)(pa + kc * 32);
      C = __builtin_amdgcn_mfma_f32_16x16x32_f16(A8, VB[kc], C, 0, 0, 0);
    }
    const int col = tn * 16 + r16;
#pragma unroll
    for (int r = 0; r < 4; ++r) {
      int row = tm * 16 + q * 4 + r;
      out[(size_t)(R0 + row) * O + col] = C[r];
    }
  }
}

extern "C" void kernel_launch(void* const* d_in, const int* in_sizes, int n_in,
                              void* d_out, int out_size, void* d_ws, size_t ws_size,
                              hipStream_t stream) {
  const float* x     = (const float*)d_in[0];
  const float* Ws    = (const float*)d_in[1];
  const float* bs    = (const float*)d_in[2];
  const float* value = (const float*)d_in[3];
  float* outp = (float*)d_out;
  float* reg_slot = outp + (size_t)8192 * O;          // index 524288
  _Float16* wt = (_Float16*)d_ws;                     // frag-major W^T fp16, 256 KB
  _Float16* vt = wt + 256 * 512;                      // frag-major value^T fp16, 32 KB

  sdt_pre<<<68, 512, 0, stream>>>(Ws, value, wt, vt, reg_slot);
  sdt_main<<<256, 512, 0, stream>>>(x, wt, vt, bs, outp, reg_slot);
}

// Round 7
// 80.828 us; speedup vs baseline: 1.4505x; 1.0133x over previous
//
#include <hip/hip_runtime.h>

// SDT forward, fp16 MFMA (fp32 accumulate), v8: v7 main dataflow +
//   (1) 2x pre parallelism (W: 128 blocks x 4 k-rows, 2 loads/thread;
//       value: 8 blocks x 32 k-rows) -> halves the pre->main serial bubble;
//   (2) vt B-frag prefetch moved to right after the K-loop (L3 latency hides
//       under the transcendental epilogue instead of phase-2c entry).
// Lessons: coop grid.sync +40us (v3); fp32 scalar gather = L2-gather-BW bound
//   +35us (v5); extra waves/SIMD no effect (v6); in-loop VMEM removal ~-0.5us
//   (v7). Main is near its structural floor; residual is pre-bubble/fixed.
// Layouts (HW-verified): A/B^T lane&15->row(n), (lane>>4)*8->k;
// C/D: col=lane&15, row=(lane>>4)*4+reg.

typedef __attribute__((ext_vector_type(8))) _Float16 half8;
typedef __attribute__((ext_vector_type(4))) _Float16 half4;
typedef __attribute__((ext_vector_type(2))) _Float16 half2v;
typedef __attribute__((ext_vector_type(4))) float floatx4;

constexpr int O = 64;
constexpr int XSTR = 520;   // x-tile LDS row stride (halfs): 1040 B
constexpr int PSTR = 280;   // P_h row stride (halfs): 560 B (16B-aligned)
constexpr int LSTR = 260;   // L_s row stride (floats)

// ---- pre: W^T fp16 frag-major; value^T fp16 frag-major; zero reg ----
// wt layout: block (T*16+c) of 1024 B; lane=(q*16+r16); elem j:
//   wt[(T*16+c)*512 + lane*8 + j] = W[k= c*32+q*8+j][n= T*16+r16]
// v8: W-path 128 blocks x 4 k-rows (2 elems/thread), value 8 blocks x 32 rows.
__global__ __launch_bounds__(512) void sdt_pre(
    const float* __restrict__ Ws, const float* __restrict__ value,
    _Float16* __restrict__ wt, _Float16* __restrict__ vt,
    float* __restrict__ reg_slot)
{
  const int bid = blockIdx.x, t = threadIdx.x;
  if (bid < 128) {                     // W: 4 k-rows per block, coalesced reads
    const int k0 = bid * 4;
    const int n = t & 255, hf = t >> 8;            // hf: which kk-pair
    const int T = n >> 4, r = n & 15;
    const int kA = k0 + hf * 2;                    // first k of this pair
    const int c = kA >> 5, q = (kA >> 3) & 3, j0 = kA & 7;
    _Float16 v2h[2];
#pragma unroll
    for (int i = 0; i < 2; ++i) {
      float f = (n < 255) ? Ws[(size_t)(kA + i) * 255 + n] : 0.f;
      v2h[i] = (_Float16)f;
    }
    *(half2v*)&wt[(size_t)(T * 16 + c) * 512 + (q * 16 + r) * 8 + j0] =
        *(half2v*)v2h;
  } else {                             // value^T: 32 k-rows per block
    const int k0 = (bid - 128) * 32;
#pragma unroll
    for (int j = 0; j < 4; ++j) {
      int e = t + j * 512;             // 0..2047
      int k = k0 + (e >> 6), n = e & 63;
      float f = value[(size_t)k * O + n];
      int T = n >> 4, r = n & 15, kc = k >> 5, q = (k >> 3) & 3, jj = k & 7;
      vt[(size_t)(T * 8 + kc) * 512 + (q * 16 + r) * 8 + jj] = (_Float16)f;
    }
    if (bid == 128 && t == 0) *reg_slot = 0.f;
  }
}

__global__ __launch_bounds__(512, 1) void sdt_main(
    const float* __restrict__ x, const _Float16* __restrict__ wt,
    const _Float16* __restrict__ vt, const float* __restrict__ bs,
    float* __restrict__ out, float* __restrict__ reg_out)
{
  // Disjoint LDS (no overlay): xh 33280 + L_s 33280 + P_h 17920 = 84480 B.
  __shared__ __align__(16) char smem[33280 + 33280 + 17920];
  _Float16* xh_s = (_Float16*)smem;               // [32][520]
  float*    L_s  = (float*)(smem + 33280);        // [32][260]
  _Float16* P_h  = (_Float16*)(smem + 66560);     // [32][280]
  __shared__ float red_s[8];

  const int t = threadIdx.x, lane = t & 63, w = t >> 6;   // 8 waves
  const int q = lane >> 4, r16 = lane & 15;
  const int R0 = blockIdx.x * 32;

  // ---- issue x loads first (HBM, longest latency; oldest -> drain first) ----
  const int xrowi = t >> 4, xl4 = (t & 15) * 4;
  const float* xrow = x + (size_t)(R0 + xrowi) * 512;
  float4 xv[8];
#pragma unroll
  for (int i = 0; i < 8; ++i) xv[i] = *(const float4*)(xrow + xl4 + i * 64);

  // ---- preload ALL 16 B-chunks for both n-tiles (128 VGPRs) ----
  const _Float16* pb0 = wt + (size_t)(2 * w) * 16 * 512 + lane * 8;
  const _Float16* pb1 = wt + (size_t)(2 * w + 1) * 16 * 512 + lane * 8;
  half8 B0[16], B1[16];
#pragma unroll
  for (int c = 0; c < 16; ++c) {
    B0[c] = *(const half8*)(pb0 + c * 512);
    B1[c] = *(const half8*)(pb1 + c * 512);
  }

  // ---- convert + store x tile to LDS ----
#pragma unroll
  for (int i = 0; i < 8; ++i) {
    half4 h = {(_Float16)xv[i].x, (_Float16)xv[i].y,
               (_Float16)xv[i].z, (_Float16)xv[i].w};
    *(half4*)&xh_s[xrowi * XSTR + xl4 + i * 64] = h;
  }
  __syncthreads();   // barrier 1: x tile staged

  // ---- K-loop: 16 chunks of K=32, pure LDS + MFMA (no VMEM) ----
  floatx4 acc00 = {0,0,0,0}, acc01 = {0,0,0,0}, acc10 = {0,0,0,0}, acc11 = {0,0,0,0};
  const int a0off = r16 * XSTR + q * 8, a1off = (16 + r16) * XSTR + q * 8;

#pragma unroll
  for (int c = 0; c < 16; ++c) {
    half8 a0 = *(const half8*)&xh_s[a0off + c * 32];
    half8 a1 = *(const half8*)&xh_s[a1off + c * 32];
    acc00 = __builtin_amdgcn_mfma_f32_16x16x32_f16(a0, B0[c], acc00, 0, 0, 0);
    acc01 = __builtin_amdgcn_mfma_f32_16x16x32_f16(a0, B1[c], acc01, 0, 0, 0);
    acc10 = __builtin_amdgcn_mfma_f32_16x16x32_f16(a1, B0[c], acc10, 0, 0, 0);
    acc11 = __builtin_amdgcn_mfma_f32_16x16x32_f16(a1, B1[c], acc11, 0, 0, 0);
  }

  // ---- vt B-frag prefetch NOW: L3 latency hides under the epilogue ----
  half8 VB[8];
  {
    const int tn = w >> 1;
    const _Float16* vb = vt + (size_t)(tn * 8) * 512 + lane * 8;
#pragma unroll
    for (int kc = 0; kc < 8; ++kc) VB[kc] = *(const half8*)(vb + kc * 512);
  }

  // ---- fused epilogue: bias + sigmoid + reg on registers ----
  const int c0 = w * 32 + r16, c1 = c0 + 16;   // c0 <= 239; c1 <= 255
  const bool v1ok = (c1 < 255);
  float pv00[4], pv01[4], pv10[4], pv11[4];
  float s0 = 0.f, s1 = 0.f;
  {
    const float b0 = bs[c0];
    const float b1 = v1ok ? bs[c1] : 0.f;
#pragma unroll
    for (int r = 0; r < 4; ++r) {
      float p;
      p = 1.f / (1.f + __expf(-(acc00[r] + b0))); pv00[r] = p;
      s0 += __logf(fmaxf(p * (1.f - p), 1e-5f));
      p = 1.f / (1.f + __expf(-(acc10[r] + b0))); pv10[r] = p;
      s0 += __logf(fmaxf(p * (1.f - p), 1e-5f));
      p = 1.f / (1.f + __expf(-(acc01[r] + b1))); pv01[r] = p;
      s1 += __logf(fmaxf(p * (1.f - p), 1e-5f));
      p = 1.f / (1.f + __expf(-(acc11[r] + b1))); pv11[r] = p;
      s1 += __logf(fmaxf(p * (1.f - p), 1e-5f));
    }
  }
  float rsum;
  {
    const int d0 = 31 - __clz(c0 + 1);
    rsum = s0 * (-0.5f / (8192.0f * (float)(1 << d0)));
    if (v1ok) {
      const int d1 = 31 - __clz(c1 + 1);
      rsum += s1 * (-0.5f / (8192.0f * (float)(1 << d1)));
    }
  }
#pragma unroll
  for (int off = 32; off; off >>= 1) rsum += __shfl_down(rsum, off, 64);

  // ---- write probabilities to L_s (disjoint from xh_s: no WAR barrier) ----
  {
#pragma unroll
    for (int r = 0; r < 4; ++r) {
      const int row0 = q * 4 + r, row1 = row0 + 16;
      L_s[row0 * LSTR + c0] = pv00[r];
      L_s[row0 * LSTR + c1] = pv01[r];   // col 255 in-bounds, never read
      L_s[row1 * LSTR + c0] = pv10[r];
      L_s[row1 * LSTR + c1] = pv11[r];
    }
    if (lane == 0) red_s[w] = rsum;
  }
  __syncthreads();   // barrier 2: L_s + red_s visible

  if (t == 0) {
    float s = 0.f;
#pragma unroll
    for (int i = 0; i < 8; ++i) s += red_s[i];
    atomicAdd(reg_out, s);
  }

  // ---- phase 2b: path products, 8 leaves x 2 rows per thread ----
  {
    const int g8 = t & 31, rp = t >> 5;
    const int Lb = g8 * 8;
#pragma unroll
    for (int rr = 0; rr < 2; ++rr) {
      const int row = rp * 2 + rr;
      const float* Lr = &L_s[row * LSTR];
      float pre = 1.f;
#pragma unroll
      for (int dd = 0; dd < 5; ++dd) {
        float p = Lr[(1 << dd) - 1 + (Lb >> (8 - dd))];
        float br = ((Lb >> (7 - dd)) & 1) ? (1.f - p) : p;
        pre *= fmaxf(br, 1e-5f);
      }
      float p5 = Lr[31 + g8];
      float s5a = fmaxf(p5, 1e-5f), s5b = fmaxf(1.f - p5, 1e-5f);
      float p6a = Lr[63 + 2 * g8], p6b = Lr[63 + 2 * g8 + 1];
      float p7v[4];
#pragma unroll
      for (int m = 0; m < 4; ++m) p7v[m] = Lr[127 + 4 * g8 + m];
      _Float16 ph[8];
#pragma unroll
      for (int j = 0; j < 8; ++j) {
        float s5 = (j & 4) ? s5b : s5a;
        float p6 = (j & 4) ? p6b : p6a;
        float s6 = fmaxf((j & 2) ? (1.f - p6) : p6, 1e-5f);
        float p7 = p7v[j >> 1];
        float s7 = fmaxf((j & 1) ? (1.f - p7) : p7, 1e-5f);
        ph[j] = (_Float16)(pre * s5 * s6 * s7);
      }
      *(half8*)&P_h[row * PSTR + Lb] = *(half8*)ph;
    }
  }
  __syncthreads();   // barrier 3: P_h ready

  // ---- phase 2c: out[32][64] = P @ value via fp16 MFMA ----
  {
    const int tm = w & 1, tn = w >> 1;       // 2 m-tiles x 4 n-tiles of 16
    floatx4 C = {0, 0, 0, 0};
    const _Float16* pa = &P_h[(tm * 16 + r16) * PSTR + q * 8];
#pragma unroll
    for (int kc = 0; kc < 8; ++kc) {
      half8 A8 = *(const half8*)(pa + kc * 32);
      C = __builtin_amdgcn_mfma_f32_16x16x32_f16(A8, VB[kc], C, 0, 0, 0);
    }
    const int col = tn * 16 + r16;
#pragma unroll
    for (int r = 0; r < 4; ++r) {
      int row = tm * 16 + q * 4 + r;
      out[(size_t)(R0 + row) * O + col] = C[r];
    }
  }
}

extern "C" void kernel_launch(void* const* d_in, const int* in_sizes, int n_in,
                              void* d_out, int out_size, void* d_ws, size_t ws_size,
                              hipStream_t stream) {
  const float* x     = (const float*)d_in[0];
  const float* Ws    = (const float*)d_in[1];
  const float* bs    = (const float*)d_in[2];
  const float* value = (const float*)d_in[3];
  float* outp = (float*)d_out;
  float* reg_slot = outp + (size_t)8192 * O;          // index 524288
  _Float16* wt = (_Float16*)d_ws;                     // frag-major W^T fp16, 256 KB
  _Float16* vt = wt + 256 * 512;                      // frag-major value^T fp16, 32 KB

  sdt_pre<<<136, 512, 0, stream>>>(Ws, value, wt, vt, reg_slot);
  sdt_main<<<256, 512, 0, stream>>>(x, wt, vt, bs, outp, reg_slot);
}